// Round 9
// baseline (197.257 us; speedup 1.0000x reference)
//
#include <hip/hip_runtime.h>
#include <hip/hip_cooperative_groups.h>
#include <cstdint>
#include <cstddef>

namespace cg = cooperative_groups;

#define MROWS 1024
#define NCOLS 4096
#define TOPK 8

typedef unsigned long long u64;

// key = (p_bits << 22) | ((1023-row) << 12) | (4095-col)
// u64 descending == p desc, then row asc, then col asc (flat-index tie-break).
__device__ inline int key_col(u64 k) { return (NCOLS - 1) - (int)(k & 0xFFFull); }
__device__ inline int key_row(u64 k) { return (MROWS - 1) - (int)((k >> 12) & 0x3FFull); }

// single-wave LDS ordering fence: wait LDS only, do NOT drain vmcnt
#define WAVE_FENCE() __asm__ volatile("s_waitcnt lgkmcnt(0)" ::: "memory")

__device__ inline float wave_sum_f(float v) {
    #pragma unroll
    for (int off = 32; off >= 1; off >>= 1)
        v += __shfl_xor(v, off, 64);
    return v;
}
__device__ inline u64 wave_max_u64(u64 v) {
    #pragma unroll
    for (int off = 32; off >= 1; off >>= 1) {
        u64 o = __shfl_xor(v, off, 64);
        v = o > v ? o : v;
    }
    return v;
}
__device__ inline u64 umax64(u64 a, u64 b) { return a > b ? a : b; }

// One cooperative kernel: exp-sum partials -> softmax policy + per-row top-8
// -> parallel dominant-edge greedy matching (exact). exp(s)/sum(exp(s)) equals
// softmax to ~2 ulps (s ~ N(0,1): no overflow); the uniform scale cannot
// reorder keys.
__global__ __launch_bounds__(1024) void k_all(const float* __restrict__ s,
                                              const int* __restrict__ cont,
                                              const int* __restrict__ prev,
                                              float* __restrict__ policy,
                                              float* __restrict__ actions,
                                              float* __restrict__ bsum,
                                              unsigned* __restrict__ bitmap,
                                              u64* __restrict__ keys8) {
    cg::grid_group grid = cg::this_grid();
    __shared__ u64 lkeys[NCOLS];               // 32 KiB; colbest in Phase C
    __shared__ u64 red[16];
    __shared__ float fredf[16];
    __shared__ unsigned coldone[NCOLS / 32];   // 128
    __shared__ unsigned rowdone[MROWS / 32];   // 32
    __shared__ float act[MROWS];               // 4 KiB
    __shared__ int exh_flag;

    int b = blockIdx.x, t = threadIdx.x;
    int wid = t >> 6, lane = t & 63;

    // ================= Phase A: exp-sum partials + bitmap ====================
    if (b == 0) {
        if (t < 128) bitmap[t] = 0u;
        __syncthreads();   // zeroing ordered before atomics
        if (cont[t]) {     // t covers all 1024 rows
            int c = prev[t];
            atomicOr(&bitmap[c >> 5], 1u << (c & 31));
        }
    }
    {
        const float4* s4 = (const float4*)s;
        float acc = 0.0f;
        #pragma unroll
        for (int q = 0; q < 4; ++q) {
            float4 v = s4[(b * 4 + q) * 1024 + t];
            acc += expf(v.x) + expf(v.y) + expf(v.z) + expf(v.w);
        }
        acc = wave_sum_f(acc);
        if (lane == 0) fredf[wid] = acc;
        __syncthreads();
        if (t == 0) {
            float ss = 0.0f;
            #pragma unroll
            for (int i = 0; i < 16; ++i) ss += fredf[i];
            bsum[b] = ss;
        }
    }
    grid.sync();

    // ================= Phase B: policy + per-row top-8 =======================
    float pv0 = (t < 256) ? bsum[t] : 0.0f;
    pv0 = wave_sum_f(pv0);
    __syncthreads();   // fredf reuse
    if (lane == 0) fredf[wid] = pv0;
    __syncthreads();
    float gsum = 0.0f;
    #pragma unroll
    for (int i = 0; i < 16; ++i) gsum += fredf[i];   // identical order in every block
    float inv = 1.0f / gsum;

    for (int q = 0; q < 4; ++q) {
        int rr = b * 4 + q;
        int cg_ = cont[rr];                 // block-uniform
        u64 rowpart = (u64)(MROWS - 1 - rr) << 12;
        const float4* srow4 = (const float4*)(s + (size_t)rr * NCOLS);
        float4* prow4 = (float4*)(policy + (size_t)rr * NCOLS);
        float4 v = srow4[t];
        float4 pv;
        pv.x = expf(v.x) * inv;
        pv.y = expf(v.y) * inv;
        pv.z = expf(v.z) * inv;
        pv.w = expf(v.w) * inv;
        prow4[t] = pv;
        int c0 = 4 * t;
        unsigned bmw = bitmap[c0 >> 5];
        float pe[4] = {pv.x, pv.y, pv.z, pv.w};
        #pragma unroll
        for (int e = 0; e < 4; ++e) {       // thread t owns lkeys[4t..4t+3]
            int c = c0 + e;
            u64 kk = 0ull;
            if (!cg_ && !((bmw >> (c & 31)) & 1u))
                kk = ((u64)__float_as_uint(pe[e]) << 22) | rowpart | (u64)(NCOLS - 1 - c);
            lkeys[c] = kk;
        }
        __syncthreads();
        if (cg_) {
            if (t < TOPK) keys8[(size_t)rr * TOPK + t] = 0ull;
            continue;                        // uniform branch; no lkeys readers
        }
        for (int pass = 0; pass < TOPK; ++pass) {
            u64 bst = umax64(umax64(lkeys[t], lkeys[t + 1024]),
                             umax64(lkeys[t + 2048], lkeys[t + 3072]));
            bst = wave_max_u64(bst);
            if (lane == 0) red[wid] = bst;
            __syncthreads();
            u64 gb = 0ull;
            #pragma unroll
            for (int i = 0; i < 16; ++i) gb = umax64(gb, red[i]);
            if (t == 0) keys8[(size_t)rr * TOPK + pass] = gb;
            int c = key_col(gb);             // gb != 0: >=3072 valid cols
            if (t == (c >> 2)) lkeys[c] = 0ull;   // owner clears
            __syncthreads();
        }
    }
    grid.sync();

    if (b != 0) return;

    // ========== Phase C: parallel dominant-edge matching (exact greedy) ======
    // Commit every key that is both its row's best surviving and its column's
    // best surviving; iterate. Distinct u64 keys => identical to serial greedy.
    u64* colbest = lkeys;
    #pragma unroll
    for (int i = 0; i < 4; ++i) colbest[t + i * 1024] = 0ull;
    if (t < 128) coldone[t] = bitmap[t];
    if (t < 32) rowdone[t] = 0u;
    if (t == 0) exh_flag = 0;
    __syncthreads();   // zeroing ordered before the atomics below

    int cgf = cont[t];
    act[t] = cgf ? (float)prev[t] : -1.0f;
    if (cgf) atomicOr(&rowdone[t >> 5], 1u << (t & 31));
    bool active = (cgf == 0);

    u64 myk[TOPK];
    {
        const u64* gk = keys8 + (size_t)t * TOPK;
        #pragma unroll
        for (int k = 0; k < TOPK; ++k) myk[k] = gk[k];
    }
    __syncthreads();

    int ki = 0;
    int anyleft = 1;
    for (int round = 0; round < 700; ++round) {
        // Phase A: advance past dead keys; submit all surviving keys
        bool subm = false;
        u64 mybest = 0ull;
        int mycol = 0;
        if (active) {
            while (ki < TOPK) {
                int c = key_col(myk[ki]);
                if (myk[ki] == 0ull ||
                    ((coldone[c >> 5] >> (c & 31)) & 1u)) { myk[ki] = 0ull; ++ki; }
                else break;
            }
            if (ki == TOPK) {
                active = false;
                exh_flag = 1;   // row needs exact fallback
            } else {
                subm = true;
                mybest = myk[ki];
                mycol = key_col(mybest);
                #pragma unroll
                for (int k = 0; k < TOPK; ++k) {
                    u64 kk = myk[k];
                    if (k < ki || kk == 0ull) continue;
                    int c = key_col(kk);
                    if ((coldone[c >> 5] >> (c & 31)) & 1u) { myk[k] = 0ull; continue; }
                    atomicMax(&colbest[c], kk);
                }
            }
        }
        anyleft = __syncthreads_count(active ? 1 : 0);
        if (anyleft == 0) break;
        // Phase B: commit dominant edges
        if (active && colbest[mycol] == mybest) {
            act[t] = (float)mycol;
            atomicOr(&coldone[mycol >> 5], 1u << (mycol & 31));
            atomicOr(&rowdone[t >> 5], 1u << (t & 31));
            active = false;
        }
        __syncthreads();
        // Phase C: clear this round's submissions
        if (subm) {
            #pragma unroll
            for (int k = 0; k < TOPK; ++k) {
                u64 kk = myk[k];
                if (k < ki || kk == 0ull) continue;
                colbest[key_col(kk)] = 0ull;
            }
        }
        __syncthreads();
    }
    __syncthreads();

    // exact-greedy fallback for exhausted rows (P ~ 1e-5): wave 0 only
    if ((exh_flag || anyleft) && t < 64) {
        int lane0 = t;
        for (int guard = 0; guard < 1200; ++guard) {
            u64 best = 0ull;
            for (int rr = 0; rr < MROWS; ++rr) {
                if ((rowdone[rr >> 5] >> (rr & 31)) & 1u) continue;
                const float* prow = policy + (size_t)rr * NCOLS;
                u64 rp = (u64)(MROWS - 1 - rr) << 12;
                for (int c = lane0; c < NCOLS; c += 64) {
                    if ((coldone[c >> 5] >> (c & 31)) & 1u) continue;
                    u64 kk = ((u64)__float_as_uint(prow[c]) << 22) | rp |
                             (u64)(NCOLS - 1 - c);
                    best = umax64(best, kk);
                }
            }
            best = wave_max_u64(best);
            if (best == 0ull) break;
            if (lane0 == 0) {
                int row = key_row(best), col = key_col(best);
                rowdone[row >> 5] |= 1u << (row & 31);
                coldone[col >> 5] |= 1u << (col & 31);
                act[row] = (float)col;
            }
            WAVE_FENCE();
        }
    }
    __syncthreads();
    actions[t] = act[t];
}

extern "C" void kernel_launch(void* const* d_in, const int* in_sizes, int n_in,
                              void* d_out, int out_size, void* d_ws, size_t ws_size,
                              hipStream_t stream) {
    (void)in_sizes; (void)n_in; (void)out_size; (void)ws_size;
    const float* scores = (const float*)d_in[0];
    const int* cont = (const int*)d_in[1];
    const int* prev = (const int*)d_in[2];
    float* out = (float*)d_out;
    float* actions = out;
    float* policy = out + MROWS;

    char* ws = (char*)d_ws;
    float* bsum = (float*)(ws + 0);              // 256 f
    unsigned* bitmap = (unsigned*)(ws + 2304);   // 128 u32
    u64* keys8 = (u64*)(ws + 4096);              // 8192 u64

    void* args[] = {(void*)&scores, (void*)&cont, (void*)&prev, (void*)&policy,
                    (void*)&actions, (void*)&bsum, (void*)&bitmap, (void*)&keys8};
    hipLaunchCooperativeKernel(reinterpret_cast<void*>(k_all),
                               dim3(256), dim3(1024), args, 0, stream);
}

// Round 10
// 107.416 us; speedup vs baseline: 1.8364x; 1.8364x over previous
//
#include <hip/hip_runtime.h>
#include <cstdint>
#include <cstddef>

#define MROWS 1024
#define NCOLS 4096
#define TOPK 8
#define NKEYS (MROWS * TOPK)   // 8192

typedef unsigned long long u64;

// key = (p_bits << 22) | ((1023-row) << 12) | (4095-col)   (54 bits used)
// u64 descending == p desc, then row asc, then col asc (flat-index tie-break).
__device__ inline int key_col(u64 k) { return (NCOLS - 1) - (int)(k & 0xFFFull); }
__device__ inline int key_row(u64 k) { return (MROWS - 1) - (int)((k >> 12) & 0x3FFull); }

// single-wave LDS ordering fence: wait LDS only, do NOT drain vmcnt
#define WAVE_FENCE() __asm__ volatile("s_waitcnt lgkmcnt(0)" ::: "memory")

__device__ inline float wave_sum_f(float v) {
    #pragma unroll
    for (int off = 32; off >= 1; off >>= 1)
        v += __shfl_xor(v, off, 64);
    return v;
}
__device__ inline u64 wave_max_u64(u64 v) {
    #pragma unroll
    for (int off = 32; off >= 1; off >>= 1) {
        u64 o = __shfl_xor(v, off, 64);
        v = o > v ? o : v;
    }
    return v;
}
__device__ inline u64 umax64(u64 a, u64 b) { return a > b ? a : b; }

// ---------------- K1: partial exp-sums (no max shift) + bitmap -----------------
// exp(s)/sum(exp(s)) == softmax(s) to ~2 ulps (s ~ N(0,1), no overflow); the
// uniform scale cannot reorder keys.
__global__ __launch_bounds__(256) void k_sum(const float* __restrict__ s,
                                             float* __restrict__ bsum,
                                             unsigned* __restrict__ bitmap,
                                             const int* __restrict__ cont,
                                             const int* __restrict__ prev) {
    int b = blockIdx.x, t = threadIdx.x;
    __shared__ float fred[4];
    if (b == 0 && t < 128) bitmap[t] = 0u;
    const float4* s4 = (const float4*)s;
    int base = b * 4096 + t;
    float acc = 0.0f;
    #pragma unroll
    for (int i = 0; i < 16; ++i) {
        float4 v = s4[base + i * 256];
        acc += expf(v.x) + expf(v.y) + expf(v.z) + expf(v.w);
    }
    acc = wave_sum_f(acc);
    if ((t & 63) == 0) fred[t >> 6] = acc;
    __syncthreads();
    if (t == 0) bsum[b] = fred[0] + fred[1] + fred[2] + fred[3];
    if (b == 0) {
        // barrier above ordered bitmap zeroing before these atomics
        for (int i = t; i < MROWS; i += 256) {
            if (cont[i]) {
                int c = prev[i];
                atomicOr(&bitmap[c >> 5], 1u << (c & 31));
            }
        }
    }
}

// ---------------- K2: policy (float4) + register-resident per-row top-8 --------
__global__ __launch_bounds__(256, 4) void k_policy_top8(const float* __restrict__ s,
                                                        const float* __restrict__ bsum,
                                                        const unsigned* __restrict__ bitmap,
                                                        const int* __restrict__ cont,
                                                        float* __restrict__ policy,
                                                        u64* __restrict__ outkeys) {
    __shared__ float fred[4];
    __shared__ u64 wavecand[4 * TOPK];   // per-wave top-8 candidates
    int r = blockIdx.x, t = threadIdx.x;
    int wid = t >> 6, lane = t & 63;

    // gsum from the 256 block partials
    float sv = bsum[t];
    sv = wave_sum_f(sv);
    if (lane == 0) fred[wid] = sv;
    __syncthreads();
    float inv = 1.0f / (fred[0] + fred[1] + fred[2] + fred[3]);

    int cg_ = cont[r];
    const float4* s4 = (const float4*)(s + (size_t)r * NCOLS);
    float4* p4 = (float4*)(policy + (size_t)r * NCOLS);
    u64 rowpart = (u64)(MROWS - 1 - r) << 12;
    u64 mykeys[16];
    #pragma unroll
    for (int i = 0; i < 4; ++i) {
        int f = t + i * 256;
        float4 v = s4[f];
        float4 pv;
        pv.x = expf(v.x) * inv;
        pv.y = expf(v.y) * inv;
        pv.z = expf(v.z) * inv;
        pv.w = expf(v.w) * inv;
        p4[f] = pv;
        int c0 = 4 * f;                       // 4 cols in one bitmap word
        unsigned bmw = bitmap[c0 >> 5];
        float pe[4] = {pv.x, pv.y, pv.z, pv.w};
        #pragma unroll
        for (int e = 0; e < 4; ++e) {
            int c = c0 + e;
            u64 kk = 0ull;
            if (!cg_ && !((bmw >> (c & 31)) & 1u))
                kk = ((u64)__float_as_uint(pe[e]) << 22) | rowpart | (u64)(NCOLS - 1 - c);
            mykeys[i * 4 + e] = kk;
        }
    }

    // per-wave top-8 (keys distinct -> unique winner each pass)
    u64 tmax = 0ull;
    #pragma unroll
    for (int k = 0; k < 16; ++k) tmax = umax64(tmax, mykeys[k]);
    for (int pass = 0; pass < TOPK; ++pass) {
        u64 w = wave_max_u64(tmax);
        if (lane == 0) wavecand[wid * TOPK + pass] = w;
        if (tmax == w && w != 0ull) {
            #pragma unroll
            for (int k = 0; k < 16; ++k)
                if (mykeys[k] == w) mykeys[k] = 0ull;
            tmax = 0ull;
            #pragma unroll
            for (int k = 0; k < 16; ++k) tmax = umax64(tmax, mykeys[k]);
        }
    }
    __syncthreads();

    // wave 0 merges the 32 candidates -> row top-8 (true top-8 of the row)
    if (wid == 0) {
        u64 val = (lane < 32) ? wavecand[lane] : 0ull;
        for (int pass = 0; pass < TOPK; ++pass) {
            u64 g = wave_max_u64(val);
            if (lane == 0) outkeys[(size_t)r * TOPK + pass] = g;   // 0 for cg_ rows
            if (val == g && g != 0ull) val = 0ull;
        }
    }
}

// ---------------- K3: parallel dominant-edge matching (exact greedy) -----------
// Commit every key that is both its row's best surviving and its column's best
// surviving; iterate. Distinct u64 keys => identical to serial greedy.
// colbest entries are tagged (round << 54) so stale rounds auto-lose: no clear
// phase, 2 barriers/round.
__global__ __launch_bounds__(1024) void k_match(const u64* __restrict__ keys_g,
                                                const int* __restrict__ cont,
                                                const int* __restrict__ prev,
                                                float* __restrict__ actions,
                                                const unsigned* __restrict__ bitmap,
                                                const float* __restrict__ policy) {
    __shared__ u64 colbest[NCOLS];             // 32 KiB
    __shared__ unsigned coldone[NCOLS / 32];   // 128 u32
    __shared__ unsigned rowdone[MROWS / 32];   // 32 u32
    __shared__ float act[MROWS];               // 4 KiB
    __shared__ int exh_flag;

    int t = threadIdx.x;   // my row
    #pragma unroll
    for (int i = 0; i < 4; ++i) colbest[t + i * 1024] = 0ull;
    if (t < 128) coldone[t] = bitmap[t];
    if (t < 32) rowdone[t] = 0u;
    if (t == 0) exh_flag = 0;
    __syncthreads();   // zeroing ordered before the atomics below

    int cgf = cont[t];
    act[t] = cgf ? (float)prev[t] : -1.0f;
    if (cgf) atomicOr(&rowdone[t >> 5], 1u << (t & 31));
    bool active = (cgf == 0);

    u64 myk[TOPK];
    {
        const u64* gk = keys_g + (size_t)t * TOPK;
        #pragma unroll
        for (int k = 0; k < TOPK; ++k) myk[k] = gk[k];
    }
    __syncthreads();

    int anyleft = 1;
    for (int round = 1; round < 1100; ++round) {
        u64 tag = (u64)round << 54;
        // Phase A: prune consumed-column keys; submit all survivors (tagged)
        bool subm = false;
        u64 mybest = 0ull;
        int mycol = 0;
        if (active) {
            u64 best = 0ull;
            #pragma unroll
            for (int k = 0; k < TOPK; ++k) {
                u64 kk = myk[k];
                if (kk != 0ull) {
                    int c = key_col(kk);
                    if ((coldone[c >> 5] >> (c & 31)) & 1u) { myk[k] = 0ull; kk = 0ull; }
                }
                best = umax64(best, kk);
            }
            if (best == 0ull) {
                active = false;
                exh_flag = 1;   // row exhausted its top-8: exact fallback
            } else {
                subm = true;
                mybest = best;
                mycol = key_col(best);
                #pragma unroll
                for (int k = 0; k < TOPK; ++k) {
                    u64 kk = myk[k];
                    if (kk != 0ull) atomicMax(&colbest[key_col(kk)], tag | kk);
                }
            }
        }
        anyleft = __syncthreads_count(active ? 1 : 0);
        if (anyleft == 0) break;
        // Phase B: commit dominant edges (row-best == col-best this round)
        if (subm && colbest[mycol] == (tag | mybest)) {
            act[t] = (float)mycol;
            atomicOr(&coldone[mycol >> 5], 1u << (mycol & 31));
            atomicOr(&rowdone[t >> 5], 1u << (t & 31));
            active = false;
        }
        __syncthreads();
    }
    __syncthreads();

    // exact-greedy fallback for exhausted rows (P ~ 1e-5): wave 0 only
    if ((exh_flag || anyleft) && t < 64) {
        int lane0 = t;
        for (int guard = 0; guard < 1200; ++guard) {
            u64 best = 0ull;
            for (int rr = 0; rr < MROWS; ++rr) {
                if ((rowdone[rr >> 5] >> (rr & 31)) & 1u) continue;
                const float* prow = policy + (size_t)rr * NCOLS;
                u64 rp = (u64)(MROWS - 1 - rr) << 12;
                for (int c = lane0; c < NCOLS; c += 64) {
                    if ((coldone[c >> 5] >> (c & 31)) & 1u) continue;
                    u64 kk = ((u64)__float_as_uint(prow[c]) << 22) | rp |
                             (u64)(NCOLS - 1 - c);
                    best = umax64(best, kk);
                }
            }
            best = wave_max_u64(best);
            if (best == 0ull) break;
            if (lane0 == 0) {
                int row = key_row(best), col = key_col(best);
                rowdone[row >> 5] |= 1u << (row & 31);
                coldone[col >> 5] |= 1u << (col & 31);
                act[row] = (float)col;
            }
            WAVE_FENCE();
        }
    }
    __syncthreads();
    actions[t] = act[t];
}

extern "C" void kernel_launch(void* const* d_in, const int* in_sizes, int n_in,
                              void* d_out, int out_size, void* d_ws, size_t ws_size,
                              hipStream_t stream) {
    (void)in_sizes; (void)n_in; (void)out_size; (void)ws_size;
    const float* scores = (const float*)d_in[0];
    const int* cont = (const int*)d_in[1];
    const int* prev = (const int*)d_in[2];
    float* out = (float*)d_out;
    float* actions = out;
    float* policy = out + MROWS;

    char* ws = (char*)d_ws;
    float* bsum = (float*)(ws + 0);              // 256 f
    unsigned* bitmap = (unsigned*)(ws + 2304);   // 128 u32
    u64* keys8 = (u64*)(ws + 4096);              // 8192 u64

    k_sum<<<256, 256, 0, stream>>>(scores, bsum, bitmap, cont, prev);
    k_policy_top8<<<MROWS, 256, 0, stream>>>(scores, bsum, bitmap, cont,
                                             policy, keys8);
    k_match<<<1, 1024, 0, stream>>>(keys8, cont, prev, actions, bitmap, policy);
}

// Round 11
// 99.924 us; speedup vs baseline: 1.9741x; 1.0750x over previous
//
#include <hip/hip_runtime.h>
#include <cstdint>
#include <cstddef>

#define MROWS 1024
#define NCOLS 4096
#define TOPK 8
#define NKEYS (MROWS * TOPK)   // 8192

typedef unsigned long long u64;
typedef unsigned int u32;

// key = (p_bits << 22) | ((1023-row) << 12) | (4095-col)   (54 bits used)
// u64 descending == p desc, then row asc, then col asc (flat-index tie-break).
__device__ inline int key_col(u64 k) { return (NCOLS - 1) - (int)(k & 0xFFFull); }
__device__ inline int key_row(u64 k) { return (MROWS - 1) - (int)((k >> 12) & 0x3FFull); }

// single-wave LDS ordering fence: wait LDS only, do NOT drain vmcnt
#define WAVE_FENCE() __asm__ volatile("s_waitcnt lgkmcnt(0)" ::: "memory")

__device__ inline float wave_sum_f(float v) {
    #pragma unroll
    for (int off = 32; off >= 1; off >>= 1)
        v += __shfl_xor(v, off, 64);
    return v;
}
__device__ inline u64 wave_max_u64(u64 v) {
    #pragma unroll
    for (int off = 32; off >= 1; off >>= 1) {
        u64 o = __shfl_xor(v, off, 64);
        v = o > v ? o : v;
    }
    return v;
}
__device__ inline u64 umax64(u64 a, u64 b) { return a > b ? a : b; }

// wave max over distinct 54-bit keys: butterfly on high-32 only, then resolve
// the (wave-uniform, rare) high-word tie on the low 32 bits.
__device__ inline u64 wave_max_key(u64 v) {
    u32 h = (u32)(v >> 32);
    u32 hm = h;
    #pragma unroll
    for (int off = 32; off >= 1; off >>= 1) {
        u32 o = __shfl_xor(hm, off, 64);
        hm = o > hm ? o : hm;
    }
    u64 tie = __ballot(h == hm);
    if ((tie & (tie - 1ull)) == 0ull) {          // unique high word (common path)
        int src = __ffsll((long long)tie) - 1;
        return __shfl(v, src, 64);
    }
    u32 l = (h == hm) ? (u32)v : 0u;
    #pragma unroll
    for (int off = 32; off >= 1; off >>= 1) {
        u32 o = __shfl_xor(l, off, 64);
        l = o > l ? o : l;
    }
    return ((u64)hm << 32) | l;
}

// ---------------- K1: partial exp-sums (no max shift) + bitmap -----------------
// exp(s)/sum(exp(s)) == softmax(s) to ~2 ulps (s ~ N(0,1), no overflow); the
// uniform scale cannot reorder keys.
__global__ __launch_bounds__(256) void k_sum(const float* __restrict__ s,
                                             float* __restrict__ bsum,
                                             unsigned* __restrict__ bitmap,
                                             const int* __restrict__ cont,
                                             const int* __restrict__ prev) {
    int b = blockIdx.x, t = threadIdx.x;
    __shared__ float fred[4];
    if (b == 0 && t < 128) bitmap[t] = 0u;
    const float4* s4 = (const float4*)s;
    int base = b * 4096 + t;
    float acc = 0.0f;
    #pragma unroll
    for (int i = 0; i < 16; ++i) {
        float4 v = s4[base + i * 256];
        acc += expf(v.x) + expf(v.y) + expf(v.z) + expf(v.w);
    }
    acc = wave_sum_f(acc);
    if ((t & 63) == 0) fred[t >> 6] = acc;
    __syncthreads();
    if (t == 0) bsum[b] = fred[0] + fred[1] + fred[2] + fred[3];
    if (b == 0) {
        // barrier above ordered bitmap zeroing before these atomics
        for (int i = t; i < MROWS; i += 256) {
            if (cont[i]) {
                int c = prev[i];
                atomicOr(&bitmap[c >> 5], 1u << (c & 31));
            }
        }
    }
}

// ---------------- K2: policy (float4) + register-resident per-row top-8 --------
__global__ __launch_bounds__(256) void k_policy_top8(const float* __restrict__ s,
                                                     const float* __restrict__ bsum,
                                                     const unsigned* __restrict__ bitmap,
                                                     const int* __restrict__ cont,
                                                     float* __restrict__ policy,
                                                     u64* __restrict__ outkeys) {
    __shared__ float fred[4];
    __shared__ u64 wavecand[4 * TOPK];   // per-wave top-8 candidates
    int r = blockIdx.x, t = threadIdx.x;
    int wid = t >> 6, lane = t & 63;

    // gsum from the 256 block partials
    float sv = bsum[t];
    sv = wave_sum_f(sv);
    if (lane == 0) fred[wid] = sv;
    __syncthreads();
    float inv = 1.0f / (fred[0] + fred[1] + fred[2] + fred[3]);

    int cg_ = cont[r];
    const float4* s4 = (const float4*)(s + (size_t)r * NCOLS);
    float4* p4 = (float4*)(policy + (size_t)r * NCOLS);
    u64 rowpart = (u64)(MROWS - 1 - r) << 12;
    u64 mykeys[16];
    #pragma unroll
    for (int i = 0; i < 4; ++i) {
        int f = t + i * 256;
        float4 v = s4[f];
        float4 pv;
        pv.x = expf(v.x) * inv;
        pv.y = expf(v.y) * inv;
        pv.z = expf(v.z) * inv;
        pv.w = expf(v.w) * inv;
        p4[f] = pv;
        int c0 = 4 * f;                       // 4 cols in one bitmap word
        unsigned bmw = bitmap[c0 >> 5];
        float pe[4] = {pv.x, pv.y, pv.z, pv.w};
        #pragma unroll
        for (int e = 0; e < 4; ++e) {
            int c = c0 + e;
            u64 kk = 0ull;
            if (!cg_ && !((bmw >> (c & 31)) & 1u))
                kk = ((u64)__float_as_uint(pe[e]) << 22) | rowpart | (u64)(NCOLS - 1 - c);
            mykeys[i * 4 + e] = kk;
        }
    }

    // per-wave top-8 (keys distinct -> unique winner each pass)
    u64 tmax = 0ull;
    #pragma unroll
    for (int k = 0; k < 16; ++k) tmax = umax64(tmax, mykeys[k]);
    for (int pass = 0; pass < TOPK; ++pass) {
        u64 w = wave_max_key(tmax);
        if (lane == 0) wavecand[wid * TOPK + pass] = w;
        if (tmax == w && w != 0ull) {         // unique winning lane
            #pragma unroll
            for (int k = 0; k < 16; ++k)
                if (mykeys[k] == w) mykeys[k] = 0ull;
            tmax = 0ull;
            #pragma unroll
            for (int k = 0; k < 16; ++k) tmax = umax64(tmax, mykeys[k]);
        }
    }
    __syncthreads();

    // wave 0 merges the 32 candidates -> row top-8 (true top-8 of the row)
    if (wid == 0) {
        u64 val = (lane < 32) ? wavecand[lane] : 0ull;
        for (int pass = 0; pass < TOPK; ++pass) {
            u64 g = wave_max_key(val);
            if (lane == 0) outkeys[(size_t)r * TOPK + pass] = g;   // 0 for cg_ rows
            if (val == g && g != 0ull) val = 0ull;
        }
    }
}

// ---------------- K3: parallel dominant-edge matching (exact greedy) -----------
// Commit every key that is both its row's best surviving and its column's best
// surviving; iterate. Distinct u64 keys => identical to serial greedy.
// colbest entries are tagged (round << 54) so stale rounds auto-lose: no clear
// phase, 2 barriers/round. round < 1024 so the tag never overflows.
__global__ __launch_bounds__(1024) void k_match(const u64* __restrict__ keys_g,
                                                const int* __restrict__ cont,
                                                const int* __restrict__ prev,
                                                float* __restrict__ actions,
                                                const unsigned* __restrict__ bitmap,
                                                const float* __restrict__ policy) {
    __shared__ u64 colbest[NCOLS];             // 32 KiB
    __shared__ unsigned coldone[NCOLS / 32];   // 128 u32
    __shared__ unsigned rowdone[MROWS / 32];   // 32 u32
    __shared__ float act[MROWS];               // 4 KiB
    __shared__ int exh_flag;

    int t = threadIdx.x;   // my row
    #pragma unroll
    for (int i = 0; i < 4; ++i) colbest[t + i * 1024] = 0ull;
    if (t < 128) coldone[t] = bitmap[t];
    if (t < 32) rowdone[t] = 0u;
    if (t == 0) exh_flag = 0;
    __syncthreads();   // zeroing ordered before the atomics below

    int cgf = cont[t];
    act[t] = cgf ? (float)prev[t] : -1.0f;
    if (cgf) atomicOr(&rowdone[t >> 5], 1u << (t & 31));
    bool active = (cgf == 0);

    u64 myk[TOPK];
    {
        const u64* gk = keys_g + (size_t)t * TOPK;
        #pragma unroll
        for (int k = 0; k < TOPK; ++k) myk[k] = gk[k];
    }
    __syncthreads();

    int anyleft = 1;
    for (int round = 1; round < 1000; ++round) {
        u64 tag = (u64)round << 54;
        // Phase A: prune consumed-column keys; submit all survivors (tagged)
        bool subm = false;
        u64 mybest = 0ull;
        int mycol = 0;
        if (active) {
            u64 best = 0ull;
            #pragma unroll
            for (int k = 0; k < TOPK; ++k) {
                u64 kk = myk[k];
                if (kk != 0ull) {
                    int c = key_col(kk);
                    if ((coldone[c >> 5] >> (c & 31)) & 1u) { myk[k] = 0ull; kk = 0ull; }
                }
                best = umax64(best, kk);
            }
            if (best == 0ull) {
                active = false;
                exh_flag = 1;   // row exhausted its top-8: exact fallback
            } else {
                subm = true;
                mybest = best;
                mycol = key_col(best);
                #pragma unroll
                for (int k = 0; k < TOPK; ++k) {
                    u64 kk = myk[k];
                    if (kk != 0ull) atomicMax(&colbest[key_col(kk)], tag | kk);
                }
            }
        }
        anyleft = __syncthreads_count(active ? 1 : 0);
        if (anyleft == 0) break;
        // Phase B: commit dominant edges (row-best == col-best this round)
        if (subm && colbest[mycol] == (tag | mybest)) {
            act[t] = (float)mycol;
            atomicOr(&coldone[mycol >> 5], 1u << (mycol & 31));
            atomicOr(&rowdone[t >> 5], 1u << (t & 31));
            active = false;
        }
        __syncthreads();
    }
    __syncthreads();

    // exact-greedy fallback for exhausted rows (P ~ 1e-5): wave 0 only
    if ((exh_flag || anyleft) && t < 64) {
        int lane0 = t;
        for (int guard = 0; guard < 1200; ++guard) {
            u64 best = 0ull;
            for (int rr = 0; rr < MROWS; ++rr) {
                if ((rowdone[rr >> 5] >> (rr & 31)) & 1u) continue;
                const float* prow = policy + (size_t)rr * NCOLS;
                u64 rp = (u64)(MROWS - 1 - rr) << 12;
                for (int c = lane0; c < NCOLS; c += 64) {
                    if ((coldone[c >> 5] >> (c & 31)) & 1u) continue;
                    u64 kk = ((u64)__float_as_uint(prow[c]) << 22) | rp |
                             (u64)(NCOLS - 1 - c);
                    best = umax64(best, kk);
                }
            }
            best = wave_max_u64(best);
            if (best == 0ull) break;
            if (lane0 == 0) {
                int row = key_row(best), col = key_col(best);
                rowdone[row >> 5] |= 1u << (row & 31);
                coldone[col >> 5] |= 1u << (col & 31);
                act[row] = (float)col;
            }
            WAVE_FENCE();
        }
    }
    __syncthreads();
    actions[t] = act[t];
}

extern "C" void kernel_launch(void* const* d_in, const int* in_sizes, int n_in,
                              void* d_out, int out_size, void* d_ws, size_t ws_size,
                              hipStream_t stream) {
    (void)in_sizes; (void)n_in; (void)out_size; (void)ws_size;
    const float* scores = (const float*)d_in[0];
    const int* cont = (const int*)d_in[1];
    const int* prev = (const int*)d_in[2];
    float* out = (float*)d_out;
    float* actions = out;
    float* policy = out + MROWS;

    char* ws = (char*)d_ws;
    float* bsum = (float*)(ws + 0);              // 256 f
    unsigned* bitmap = (unsigned*)(ws + 2304);   // 128 u32
    u64* keys8 = (u64*)(ws + 4096);              // 8192 u64

    k_sum<<<256, 256, 0, stream>>>(scores, bsum, bitmap, cont, prev);
    k_policy_top8<<<MROWS, 256, 0, stream>>>(scores, bsum, bitmap, cont,
                                             policy, keys8);
    k_match<<<1, 1024, 0, stream>>>(keys8, cont, prev, actions, bitmap, policy);
}

// Round 12
// 95.745 us; speedup vs baseline: 2.0602x; 1.0437x over previous
//
#include <hip/hip_runtime.h>
#include <cstdint>
#include <cstddef>

#define MROWS 1024
#define NCOLS 4096
#define TOPK 8
#define NKEYS (MROWS * TOPK)   // 8192

typedef unsigned long long u64;
typedef unsigned int u32;

// Order-preserving float->u32 map (total order, matches score order exactly;
// bit-equal scores -> equal ord, tie then broken by row/col = flat index).
__device__ inline u32 fkey(u32 b) { return (b & 0x80000000u) ? ~b : (b | 0x80000000u); }

// key = (ord << 22) | ((1023-row) << 12) | (4095-col)   (54 bits used)
// u64 descending == score desc, then row asc, then col asc (flat-index tie-break).
__device__ inline int key_col(u64 k) { return (NCOLS - 1) - (int)(k & 0xFFFull); }
__device__ inline int key_row(u64 k) { return (MROWS - 1) - (int)((k >> 12) & 0x3FFull); }

// single-wave LDS ordering fence: wait LDS only, do NOT drain vmcnt
#define WAVE_FENCE() __asm__ volatile("s_waitcnt lgkmcnt(0)" ::: "memory")

__device__ inline float wave_sum_f(float v) {
    #pragma unroll
    for (int off = 32; off >= 1; off >>= 1)
        v += __shfl_xor(v, off, 64);
    return v;
}
__device__ inline u64 wave_max_u64(u64 v) {
    #pragma unroll
    for (int off = 32; off >= 1; off >>= 1) {
        u64 o = __shfl_xor(v, off, 64);
        v = o > v ? o : v;
    }
    return v;
}
__device__ inline u64 umax64(u64 a, u64 b) { return a > b ? a : b; }

// wave max over distinct 54-bit keys: butterfly on high-32 only, then resolve
// the (wave-uniform, rare) high-word tie on the low 32 bits.
__device__ inline u64 wave_max_key(u64 v) {
    u32 h = (u32)(v >> 32);
    u32 hm = h;
    #pragma unroll
    for (int off = 32; off >= 1; off >>= 1) {
        u32 o = __shfl_xor(hm, off, 64);
        hm = o > hm ? o : hm;
    }
    u64 tie = __ballot(h == hm);
    if ((tie & (tie - 1ull)) == 0ull) {          // unique high word (common path)
        int src = __ffsll((long long)tie) - 1;
        return __shfl(v, src, 64);
    }
    u32 l = (h == hm) ? (u32)v : 0u;
    #pragma unroll
    for (int off = 32; off >= 1; off >>= 1) {
        u32 o = __shfl_xor(l, off, 64);
        l = o > l ? o : l;
    }
    return ((u64)hm << 32) | l;
}

// ---------------- K1: per-row top-8 score-keys + exp-sum + bitmap --------------
// exp(s)/sum(exp(s)) == softmax(s) to ~2 ulps (s ~ N(0,1), no overflow); the
// uniform scale cannot reorder values, so score order == policy order.
__global__ __launch_bounds__(256) void k_prep(const float* __restrict__ s,
                                              const int* __restrict__ cont,
                                              const int* __restrict__ prev,
                                              float* __restrict__ rowsum,
                                              unsigned* __restrict__ bitmap_g,
                                              u64* __restrict__ outkeys) {
    __shared__ unsigned lbm[NCOLS / 32];   // 128: consumed-column bitmap (local)
    __shared__ u64 wavecand[4 * TOPK];
    __shared__ float fred[4];
    int r = blockIdx.x, t = threadIdx.x;
    int wid = t >> 6, lane = t & 63;

    if (t < 128) lbm[t] = 0u;
    __syncthreads();
    for (int i = t; i < MROWS; i += 256) {
        if (cont[i]) {
            int c = prev[i];
            atomicOr(&lbm[c >> 5], 1u << (c & 31));
        }
    }
    __syncthreads();
    if (r == 0 && t < 128) bitmap_g[t] = lbm[t];   // export for K2's match block

    int cg_ = cont[r];
    const float4* s4 = (const float4*)(s + (size_t)r * NCOLS);
    u64 rowpart = (u64)(MROWS - 1 - r) << 12;
    u64 mykeys[16];
    float acc = 0.0f;
    #pragma unroll
    for (int i = 0; i < 4; ++i) {
        int f = t + i * 256;
        float4 v = s4[f];
        acc += expf(v.x) + expf(v.y) + expf(v.z) + expf(v.w);
        int c0 = 4 * f;
        unsigned bmw = lbm[c0 >> 5];
        float se[4] = {v.x, v.y, v.z, v.w};
        #pragma unroll
        for (int e = 0; e < 4; ++e) {
            int c = c0 + e;
            u64 kk = 0ull;
            if (!cg_ && !((bmw >> (c & 31)) & 1u))
                kk = ((u64)fkey(__float_as_uint(se[e])) << 22) | rowpart |
                     (u64)(NCOLS - 1 - c);
            mykeys[i * 4 + e] = kk;
        }
    }
    // per-row exp-sum partial
    acc = wave_sum_f(acc);
    if (lane == 0) fred[wid] = acc;
    __syncthreads();
    if (t == 0) rowsum[r] = fred[0] + fred[1] + fred[2] + fred[3];

    // per-wave top-8 (keys distinct -> unique winner each pass)
    u64 tmax = 0ull;
    #pragma unroll
    for (int k = 0; k < 16; ++k) tmax = umax64(tmax, mykeys[k]);
    for (int pass = 0; pass < TOPK; ++pass) {
        u64 w = wave_max_key(tmax);
        if (lane == 0) wavecand[wid * TOPK + pass] = w;
        if (tmax == w && w != 0ull) {
            #pragma unroll
            for (int k = 0; k < 16; ++k)
                if (mykeys[k] == w) mykeys[k] = 0ull;
            tmax = 0ull;
            #pragma unroll
            for (int k = 0; k < 16; ++k) tmax = umax64(tmax, mykeys[k]);
        }
    }
    __syncthreads();
    // wave 0 merges the 32 candidates -> true row top-8
    if (wid == 0) {
        u64 val = (lane < 32) ? wavecand[lane] : 0ull;
        for (int pass = 0; pass < TOPK; ++pass) {
            u64 g = wave_max_key(val);
            if (lane == 0) outkeys[(size_t)r * TOPK + pass] = g;   // 0 for cg_ rows
            if (val == g && g != 0ull) val = 0ull;
        }
    }
}

// ---------------- K2: block 0 = dominant-edge match; blocks 1..1024 = policy ---
// Match commits every key that is both its row's best surviving and its
// column's best surviving; iterate. Distinct u64 keys => identical to serial
// greedy. colbest entries tagged (round << 54) so stale rounds auto-lose.
__global__ __launch_bounds__(1024) void k_policy_match(const float* __restrict__ s,
                                                       const int* __restrict__ cont,
                                                       const int* __restrict__ prev,
                                                       const float* __restrict__ rowsum,
                                                       const unsigned* __restrict__ bitmap,
                                                       const u64* __restrict__ keys_g,
                                                       float* __restrict__ policy,
                                                       float* __restrict__ actions) {
    __shared__ u64 colbest[NCOLS];             // 32 KiB (match only)
    __shared__ unsigned coldone[NCOLS / 32];   // 128
    __shared__ unsigned rowdone[MROWS / 32];   // 32
    __shared__ float act[MROWS];               // 4 KiB
    __shared__ float fredf[16];
    __shared__ int exh_flag;

    int t = threadIdx.x;

    if (blockIdx.x != 0) {
        // ---------------- policy row write ----------------
        int wid = t >> 6, lane = t & 63;
        float sv = rowsum[t];                  // 1024 partials, one per thread
        sv = wave_sum_f(sv);
        if (lane == 0) fredf[wid] = sv;
        __syncthreads();
        float g = 0.0f;
        #pragma unroll
        for (int i = 0; i < 16; ++i) g += fredf[i];   // same order every block
        float inv = 1.0f / g;
        int r = blockIdx.x - 1;
        const float4* srow4 = (const float4*)(s + (size_t)r * NCOLS);
        float4* prow4 = (float4*)(policy + (size_t)r * NCOLS);
        float4 v = srow4[t];                   // 1024 float4 = whole row
        float4 pv;
        pv.x = expf(v.x) * inv;
        pv.y = expf(v.y) * inv;
        pv.z = expf(v.z) * inv;
        pv.w = expf(v.w) * inv;
        prow4[t] = pv;
        return;
    }

    // ---------------- match (block 0, scheduled first) ----------------
    #pragma unroll
    for (int i = 0; i < 4; ++i) colbest[t + i * 1024] = 0ull;
    if (t < 128) coldone[t] = bitmap[t];
    if (t < 32) rowdone[t] = 0u;
    if (t == 0) exh_flag = 0;
    __syncthreads();   // zeroing ordered before the atomics below

    int cgf = cont[t];
    act[t] = cgf ? (float)prev[t] : -1.0f;
    if (cgf) atomicOr(&rowdone[t >> 5], 1u << (t & 31));
    bool active = (cgf == 0);

    u64 myk[TOPK];
    {
        const u64* gk = keys_g + (size_t)t * TOPK;
        #pragma unroll
        for (int k = 0; k < TOPK; ++k) myk[k] = gk[k];
    }
    __syncthreads();

    int anyleft = 1;
    for (int round = 1; round < 1000; ++round) {
        u64 tag = (u64)round << 54;
        bool subm = false;
        u64 mybest = 0ull;
        int mycol = 0;
        if (active) {
            u64 best = 0ull;
            #pragma unroll
            for (int k = 0; k < TOPK; ++k) {
                u64 kk = myk[k];
                if (kk != 0ull) {
                    int c = key_col(kk);
                    if ((coldone[c >> 5] >> (c & 31)) & 1u) { myk[k] = 0ull; kk = 0ull; }
                }
                best = umax64(best, kk);
            }
            if (best == 0ull) {
                active = false;
                exh_flag = 1;   // row exhausted its top-8: exact fallback
            } else {
                subm = true;
                mybest = best;
                mycol = key_col(best);
                #pragma unroll
                for (int k = 0; k < TOPK; ++k) {
                    u64 kk = myk[k];
                    if (kk != 0ull) atomicMax(&colbest[key_col(kk)], tag | kk);
                }
            }
        }
        anyleft = __syncthreads_count(active ? 1 : 0);
        if (anyleft == 0) break;
        if (subm && colbest[mycol] == (tag | mybest)) {
            act[t] = (float)mycol;
            atomicOr(&coldone[mycol >> 5], 1u << (mycol & 31));
            atomicOr(&rowdone[t >> 5], 1u << (t & 31));
            active = false;
        }
        __syncthreads();
    }
    __syncthreads();

    // exact-greedy fallback for exhausted rows (P ~ 1e-5): wave 0, score keys
    if ((exh_flag || anyleft) && t < 64) {
        int lane0 = t;
        for (int guard = 0; guard < 1200; ++guard) {
            u64 best = 0ull;
            for (int rr = 0; rr < MROWS; ++rr) {
                if ((rowdone[rr >> 5] >> (rr & 31)) & 1u) continue;
                const float* srow = s + (size_t)rr * NCOLS;
                u64 rp = (u64)(MROWS - 1 - rr) << 12;
                for (int c = lane0; c < NCOLS; c += 64) {
                    if ((coldone[c >> 5] >> (c & 31)) & 1u) continue;
                    u64 kk = ((u64)fkey(__float_as_uint(srow[c])) << 22) | rp |
                             (u64)(NCOLS - 1 - c);
                    best = umax64(best, kk);
                }
            }
            best = wave_max_u64(best);
            if (best == 0ull) break;
            if (lane0 == 0) {
                int row = key_row(best), col = key_col(best);
                rowdone[row >> 5] |= 1u << (row & 31);
                coldone[col >> 5] |= 1u << (col & 31);
                act[row] = (float)col;
            }
            WAVE_FENCE();
        }
    }
    __syncthreads();
    actions[t] = act[t];
}

extern "C" void kernel_launch(void* const* d_in, const int* in_sizes, int n_in,
                              void* d_out, int out_size, void* d_ws, size_t ws_size,
                              hipStream_t stream) {
    (void)in_sizes; (void)n_in; (void)out_size; (void)ws_size;
    const float* scores = (const float*)d_in[0];
    const int* cont = (const int*)d_in[1];
    const int* prev = (const int*)d_in[2];
    float* out = (float*)d_out;
    float* actions = out;
    float* policy = out + MROWS;

    char* ws = (char*)d_ws;
    float* rowsum = (float*)(ws + 0);            // 1024 f
    unsigned* bitmap = (unsigned*)(ws + 4096);   // 128 u32
    u64* keys8 = (u64*)(ws + 8192);              // 8192 u64

    k_prep<<<MROWS, 256, 0, stream>>>(scores, cont, prev, rowsum, bitmap, keys8);
    k_policy_match<<<MROWS + 1, 1024, 0, stream>>>(scores, cont, prev, rowsum,
                                                   bitmap, keys8, policy, actions);
}